// Round 2
// baseline (705.127 us; speedup 1.0000x reference)
//
#include <hip/hip_runtime.h>

typedef __bf16 bf16_t;
typedef bf16_t bf16x8 __attribute__((ext_vector_type(8)));
typedef float f32x4 __attribute__((ext_vector_type(4)));

#define BATCH 16384
#define HID 256

// ---------- bf16 helpers ----------
__device__ __forceinline__ ushort f2b(float f) {
  union { float f; unsigned u; } v; v.f = f;
  unsigned u = v.u;
  unsigned r = (u + 0x7fffu + ((u >> 16) & 1u)) >> 16;
  return (ushort)r;
}
__device__ __forceinline__ float b2f(ushort u) {
  union { unsigned u; float f; } v; v.u = ((unsigned)u) << 16; return v.f;
}
__device__ __forceinline__ void loadbf4(const ushort* __restrict__ p, float* o) {
  uint2 q = *(const uint2*)p;
  o[0] = b2f((ushort)(q.x & 0xffffu));
  o[1] = b2f((ushort)(q.x >> 16));
  o[2] = b2f((ushort)(q.y & 0xffffu));
  o[3] = b2f((ushort)(q.y >> 16));
}
__device__ __forceinline__ uint2 packbf4(const float* v) {
  uint2 q;
  q.x = (unsigned)f2b(v[0]) | ((unsigned)f2b(v[1]) << 16);
  q.y = (unsigned)f2b(v[2]) | ((unsigned)f2b(v[3]) << 16);
  return q;
}

// async global->LDS, 16B per lane; lds base must be wave-uniform
__device__ __forceinline__ void gll16(const ushort* g, ushort* l) {
  __builtin_amdgcn_global_load_lds((const __attribute__((address_space(1))) void*)g,
                                   (__attribute__((address_space(3))) void*)l, 16, 0, 0);
}

// ---------- convert fp32 -> bf16 ----------
__global__ __launch_bounds__(256)
void f2b_kernel(const float* __restrict__ in, ushort* __restrict__ out) {
  int t = blockIdx.x * 256 + threadIdx.x;
  float4 v = *(const float4*)(in + (size_t)t * 4);
  float a[4] = {v.x, v.y, v.z, v.w};
  *(uint2*)(out + (size_t)t * 4) = packbf4(a);
}

// ---------- transposed bf16 weights: Wt[ksel*256+d][h] = W[ksel][h][d] ----------
__global__ __launch_bounds__(256)
void wt_kernel(const float* __restrict__ W, ushort* __restrict__ Wt) {
  int idx = blockIdx.x * 256 + threadIdx.x;
  int c = idx >> 8, hh = idx & 255;
  int ks = c >> 8, d = c & 255;
  Wt[idx] = f2b(W[ks * 65536 + hh * 256 + d]);
}

// ---------- fused dual-GEMM + epilogue ----------
// C1 = A1 @ W1t, C2 = A2 @ W2t per 128x128 tile, K=256.
// MODE 0: cand = C1+C2+b     -> PcA, scoreA
// MODE 2: cand = C1*C2+b     -> PcA, scoreA
// MODE 3: sigmoid(C1+C2+b), N=512 -> gnode slots 0/1/2 + z1b/rb  (no scores)
// MODE 4: candA = 1-(C2+b) -> PcA,scoreA ; candB = C1*C2+b -> PcB,scoreB
template<int MODE>
__global__ __launch_bounds__(256, 2)
void dgemm_kernel(const ushort* __restrict__ A1, const ushort* __restrict__ W1,
                  const ushort* __restrict__ A2, const ushort* __restrict__ W2,
                  const float* __restrict__ bias, const float* __restrict__ Ws,
                  ushort* __restrict__ PcA, ushort* __restrict__ PcB,
                  float* __restrict__ scoreA, float* __restrict__ scoreB,
                  float* __restrict__ gnode, ushort* __restrict__ z1b,
                  ushort* __restrict__ rb) {
  __shared__ ushort As1[4096], As2[4096], Bs1[4096], Bs2[4096];  // [128 rows][32 k]
  __shared__ float sbuf[2][128][2];
  const int tid  = threadIdx.x;
  const int lane = tid & 63;
  const int w    = tid >> 6;
  const int bm   = blockIdx.y * 128;
  const int bnc  = blockIdx.x * 128;

  // staging map: inst (w,j) covers rows (w+j*4)*16..+16, lane -> row=r0+(lane>>2), chunk=lane&3
  // swizzle: stored chunk = c ^ (rl&3) ^ ((rl>>2)&3)  (consistent with frag read below)
  const int rl = lane >> 2, cc = lane & 3;
  const int cs = (cc ^ (rl & 3) ^ ((rl >> 2) & 3)) * 8;   // element offset
  const int sr0 = w * 16 + rl, sr1 = sr0 + 64;
  const ushort* a1g0 = A1 + (size_t)(bm + sr0) * 256 + cs;
  const ushort* a1g1 = A1 + (size_t)(bm + sr1) * 256 + cs;
  const ushort* a2g0 = A2 + (size_t)(bm + sr0) * 256 + cs;
  const ushort* a2g1 = A2 + (size_t)(bm + sr1) * 256 + cs;
  const ushort* w1g0 = W1 + (size_t)(bnc + sr0) * 256 + cs;
  const ushort* w1g1 = W1 + (size_t)(bnc + sr1) * 256 + cs;
  const ushort* w2g0 = W2 + (size_t)(bnc + sr0) * 256 + cs;
  const ushort* w2g1 = W2 + (size_t)(bnc + sr1) * 256 + cs;
  ushort* lA1_0 = &As1[w * 512]; ushort* lA1_1 = &As1[(w + 4) * 512];
  ushort* lA2_0 = &As2[w * 512]; ushort* lA2_1 = &As2[(w + 4) * 512];
  ushort* lB1_0 = &Bs1[w * 512]; ushort* lB1_1 = &Bs1[(w + 4) * 512];
  ushort* lB2_0 = &Bs2[w * 512]; ushort* lB2_1 = &Bs2[(w + 4) * 512];

  // frag constants
  const int row15 = lane & 15, quad = lane >> 4;
  const int fs = (quad ^ (row15 & 3) ^ ((row15 >> 2) & 3)) * 8;  // element offset in row
  const int wm = (w >> 1) * 64, wn = (w & 1) * 64;

  f32x4 acc1[4][4] = {}, acc2[4][4] = {};

  for (int kt = 0; kt < 8; ++kt) {
    const int k0 = kt * 32;
    __syncthreads();                       // LDS readers of kt-1 done
    gll16(a1g0 + k0, lA1_0); gll16(a1g1 + k0, lA1_1);
    gll16(a2g0 + k0, lA2_0); gll16(a2g1 + k0, lA2_1);
    gll16(w1g0 + k0, lB1_0); gll16(w1g1 + k0, lB1_1);
    gll16(w2g0 + k0, lB2_0); gll16(w2g1 + k0, lB2_1);
    __syncthreads();                       // compiler drains vmcnt before barrier
    bf16x8 b1[4], b2[4];
    for (int tj = 0; tj < 4; ++tj) {
      b1[tj] = *(const bf16x8*)&Bs1[(wn + tj * 16 + row15) * 32 + fs];
      b2[tj] = *(const bf16x8*)&Bs2[(wn + tj * 16 + row15) * 32 + fs];
    }
    for (int ti = 0; ti < 4; ++ti) {
      bf16x8 a1f = *(const bf16x8*)&As1[(wm + ti * 16 + row15) * 32 + fs];
      bf16x8 a2f = *(const bf16x8*)&As2[(wm + ti * 16 + row15) * 32 + fs];
      for (int tj = 0; tj < 4; ++tj) {
        acc1[ti][tj] = __builtin_amdgcn_mfma_f32_16x16x32_bf16(a1f, b1[tj], acc1[ti][tj], 0, 0, 0);
        acc2[ti][tj] = __builtin_amdgcn_mfma_f32_16x16x32_bf16(a2f, b2[tj], acc2[ti][tj], 0, 0, 0);
      }
    }
  }

  if constexpr (MODE == 3) {
    const bool isz = (bnc < 256);          // block-uniform: z1 cols [0,256), r cols [256,512)
    for (int ti = 0; ti < 4; ++ti)
      for (int tj = 0; tj < 4; ++tj) {
        int gnc = bnc + wn + tj * 16 + row15;
        float bb = bias[gnc];
        for (int r2 = 0; r2 < 4; ++r2) {
          int gm = bm + wm + ti * 16 + quad * 4 + r2;
          float v = 1.0f / (1.0f + expf(-(acc1[ti][tj][r2] + acc2[ti][tj][r2] + bb)));
          if (isz) {
            gnode[(size_t)gm * 2304 + gnc] = v;          // slot 0 (z1)
            gnode[(size_t)gm * 2304 + 512 + gnc] = v;    // slot 2 (z2 == z1)
            z1b[(size_t)gm * 256 + gnc] = f2b(v);
          } else {
            int d = gnc - 256;
            gnode[(size_t)gm * 2304 + 256 + d] = v;      // slot 1 (r)
            rb[(size_t)gm * 256 + d] = f2b(v);
          }
        }
      }
  } else {
    float wsv[4], bv[4]; int gnc4[4];
    for (int tj = 0; tj < 4; ++tj) {
      int gnc = bnc + wn + tj * 16 + row15;
      gnc4[tj] = gnc; wsv[tj] = Ws[gnc & 255]; bv[tj] = bias[gnc];
    }
    float pA[4][4], pB[4][4];
    for (int ti = 0; ti < 4; ++ti) {
      int gm0 = bm + wm + ti * 16 + quad * 4;
      for (int r2 = 0; r2 < 4; ++r2) { pA[ti][r2] = 0.f; pB[ti][r2] = 0.f; }
      for (int tj = 0; tj < 4; ++tj)
        for (int r2 = 0; r2 < 4; ++r2) {
          float c1 = acc1[ti][tj][r2], c2 = acc2[ti][tj][r2];
          float ca;
          if constexpr (MODE == 0) ca = c1 + c2 + bv[tj];
          else if constexpr (MODE == 2) ca = c1 * c2 + bv[tj];
          else ca = 1.0f - (c2 + bv[tj]);
          PcA[(size_t)(gm0 + r2) * 1024 + gnc4[tj]] = f2b(ca);
          pA[ti][r2] += ca * wsv[tj];
          if constexpr (MODE == 4) {
            float cb = c1 * c2 + bv[tj];
            PcB[(size_t)(gm0 + r2) * 1024 + gnc4[tj]] = f2b(cb);
            pB[ti][r2] += cb * wsv[tj];
          }
        }
    }
    for (int ti = 0; ti < 4; ++ti)
      for (int r2 = 0; r2 < 4; ++r2) {
        float v = pA[ti][r2];
        v += __shfl_xor(v, 1, 64); v += __shfl_xor(v, 2, 64);
        v += __shfl_xor(v, 4, 64); v += __shfl_xor(v, 8, 64);
        if (row15 == 0) sbuf[0][wm + ti * 16 + quad * 4 + r2][wn >> 6] = v;
        if constexpr (MODE == 4) {
          float u = pB[ti][r2];
          u += __shfl_xor(u, 1, 64); u += __shfl_xor(u, 2, 64);
          u += __shfl_xor(u, 4, 64); u += __shfl_xor(u, 8, 64);
          if (row15 == 0) sbuf[1][wm + ti * 16 + quad * 4 + r2][wn >> 6] = u;
        }
      }
    __syncthreads();
    if (tid < 128) {
      scoreA[(size_t)(bm + tid) * 8 + blockIdx.x] = sbuf[0][tid][0] + sbuf[0][tid][1];
      if constexpr (MODE == 4)
        scoreB[(size_t)(bm + tid) * 8 + blockIdx.x] = sbuf[1][tid][0] + sbuf[1][tid][1];
    }
  }
}

// ---------- light mixture: softmax from score halves, weighted sum of cand ----------
__global__ __launch_bounds__(256)
void lmix_kernel(const ushort* __restrict__ Pc, const float* __restrict__ sb,
                 float* __restrict__ gnode, ushort* __restrict__ actout,
                 float* __restrict__ hnext, float* __restrict__ part) {
  const int tid = threadIdx.x, wave = tid >> 6, lane = tid & 63;
  const int row = blockIdx.x * 4 + wave;
  const int d0 = lane * 4;
  const float* sp = sb + (size_t)row * 8;
  float s0 = sp[0] + sp[1], s1 = sp[2] + sp[3], s2 = sp[4] + sp[5], s3 = sp[6] + sp[7];
  float mx = fmaxf(fmaxf(s0, s1), fmaxf(s2, s3));
  float e0 = expf(s0 - mx), e1 = expf(s1 - mx), e2 = expf(s2 - mx), e3 = expf(s3 - mx);
  float inv = 1.0f / (e0 + e1 + e2 + e3);
  float w0 = e0 * inv, w1 = e1 * inv, w2 = e2 * inv, w3 = e3 * inv;
  float c0[4], c1[4], c2[4], c3[4];
  loadbf4(Pc + (size_t)row * 1024 + 0 + d0, c0);
  loadbf4(Pc + (size_t)row * 1024 + 256 + d0, c1);
  loadbf4(Pc + (size_t)row * 1024 + 512 + d0, c2);
  loadbf4(Pc + (size_t)row * 1024 + 768 + d0, c3);
  float o[4];
  for (int i = 0; i < 4; ++i) o[i] = w0 * c0[i] + w1 * c1[i] + w2 * c2[i] + w3 * c3[i];
  size_t g = (size_t)row * 2304 + d0;   // gnode already slot-offset; 4B-aligned base
  for (int i = 0; i < 4; ++i) gnode[g + i] = o[i];
  if (actout) *(uint2*)(actout + (size_t)row * 256 + d0) = packbf4(o);
  if (hnext) { float4 ov = {o[0], o[1], o[2], o[3]}; *(float4*)(hnext + (size_t)row * 256 + d0) = ov; }
  __shared__ float sred[4][4];
  if (lane == 0) { sred[wave][0] = s0; sred[wave][1] = s1; sred[wave][2] = s2; sred[wave][3] = s3; }
  __syncthreads();
  if (tid < 4)
    part[blockIdx.x * 4 + tid] = sred[0][tid] + sred[1][tid] + sred[2][tid] + sred[3][tid];
}

// ---------- finalize ----------
__global__ __launch_bounds__(256)
void fin_kernel(const float* __restrict__ part, float* __restrict__ gs,
                float* __restrict__ margins) {
  __shared__ float red[256][4];
  __shared__ float sfin[6][4];
  int tid = threadIdx.x;
  for (int si = 0; si < 6; ++si) {
    float a[4] = {0.f, 0.f, 0.f, 0.f};
    for (int i = 0; i < 16; ++i) {
      const float* p = part + ((size_t)si * 4096 + tid + 256 * i) * 4;
      for (int k = 0; k < 4; ++k) a[k] += p[k];
    }
    for (int k = 0; k < 4; ++k) red[tid][k] = a[k];
    __syncthreads();
    for (int st = 128; st >= 1; st >>= 1) {
      if (tid < st) for (int k = 0; k < 4; ++k) red[tid][k] += red[tid + st][k];
      __syncthreads();
    }
    if (tid == 0) for (int k = 0; k < 4; ++k) sfin[si][k] = red[0][k];
    __syncthreads();
  }
  if (tid == 0) {
    gs[0] = 0.f; gs[1] = 1.f; gs[2] = 0.f;
    for (int si = 0; si < 6; ++si) {
      float s[4] = {sfin[si][0], sfin[si][1], sfin[si][2], sfin[si][3]};
      int idx = 0; float best = s[0];
      for (int k = 1; k < 4; ++k) if (s[k] > best) { best = s[k]; idx = k; }
      float second = -3.4e38f;
      for (int k = 0; k < 4; ++k) if (k != idx) second = fmaxf(second, s[k]);
      gs[3 + si] = (float)idx;
      margins[si] = best - second;
    }
  }
}

extern "C" void kernel_launch(void* const* d_in, const int* in_sizes, int n_in,
                              void* d_out, int out_size, void* d_ws, size_t ws_size,
                              hipStream_t stream) {
  const float* x    = (const float*)d_in[0];
  const float* h    = (const float*)d_in[1];
  const float* L    = (const float*)d_in[2];
  const float* R    = (const float*)d_in[3];
  const float* bias = (const float*)d_in[4];
  const float* Ws   = (const float*)d_in[5];

  float* out        = (float*)d_out;
  float* out_hnext  = out;                          // 4,194,304
  float* out_gs     = out + 4194304;                // 9
  float* out_gnode  = out + 4194313;                // 16384*9*256
  float* out_marg   = out + 41943049;               // 6

  ushort* Pc0  = (ushort*)d_ws;                     // B*1024 each
  ushort* Pc1  = Pc0 + (size_t)BATCH * 1024;
  ushort* Pc2  = Pc1 + (size_t)BATCH * 1024;
  ushort* x2b  = Pc2 + (size_t)BATCH * 1024;
  ushort* h2b  = x2b + (size_t)BATCH * HID;
  ushort* z1b  = h2b + (size_t)BATCH * HID;
  ushort* rb   = z1b + (size_t)BATCH * HID;
  ushort* rhb  = rb  + (size_t)BATCH * HID;
  ushort* htb  = rhb + (size_t)BATCH * HID;
  ushort* omzb = htb + (size_t)BATCH * HID;
  ushort* ztb  = omzb + (size_t)BATCH * HID;
  ushort* z2hb = ztb + (size_t)BATCH * HID;
  ushort* Lt   = z2hb + (size_t)BATCH * HID;        // 1024*256
  ushort* Rt   = Lt + 1024 * 256;
  float*  scA  = (float*)(Rt + 1024 * 256);         // [16384][8]
  float*  scB  = scA + (size_t)BATCH * 8;
  float*  part = scB + (size_t)BATCH * 8;           // 6*4096*4

  dim3 gmix(8, 128), gsig(4, 128);

  f2b_kernel<<<4096, 256, 0, stream>>>(x, x2b);
  f2b_kernel<<<4096, 256, 0, stream>>>(h, h2b);
  wt_kernel<<<1024, 256, 0, stream>>>(L, Lt);
  wt_kernel<<<1024, 256, 0, stream>>>(R, Rt);

  // sig: z1 = sig(x@L0 + h@R0), r = sig(x@L1 + h@R1)
  dgemm_kernel<3><<<gsig, 256, 0, stream>>>(x2b, Lt, h2b, Rt, bias, nullptr,
      nullptr, nullptr, nullptr, nullptr, out_gnode, z1b, rb);

  // rh = mix(h@L + r@R + b)
  dgemm_kernel<0><<<gmix, 256, 0, stream>>>(h2b, Lt, rb, Rt, bias, Ws,
      Pc0, nullptr, scA, nullptr, nullptr, nullptr, nullptr);
  lmix_kernel<<<4096, 256, 0, stream>>>(Pc0, scA, out_gnode + 3 * 256, rhb,
      nullptr, part + 0 * 4096 * 4);

  // h_tilde = mix(x@L + rh@R + b)
  dgemm_kernel<0><<<gmix, 256, 0, stream>>>(x2b, Lt, rhb, Rt, bias, Ws,
      Pc0, nullptr, scA, nullptr, nullptr, nullptr, nullptr);
  lmix_kernel<<<4096, 256, 0, stream>>>(Pc0, scA, out_gnode + 4 * 256, htb,
      nullptr, part + 1 * 4096 * 4);

  // omz = mix(1-(z1@R+b)) and z2h = mix(h@L * z1@R + b) in one pass
  dgemm_kernel<4><<<gmix, 256, 0, stream>>>(h2b, Lt, z1b, Rt, bias, Ws,
      Pc1, Pc2, scA, scB, nullptr, nullptr, nullptr);
  lmix_kernel<<<4096, 256, 0, stream>>>(Pc1, scA, out_gnode + 5 * 256, omzb,
      nullptr, part + 2 * 4096 * 4);
  lmix_kernel<<<4096, 256, 0, stream>>>(Pc2, scB, out_gnode + 7 * 256, z2hb,
      nullptr, part + 4 * 4096 * 4);

  // zh_tilde = mix(ht@L * omz@R + b)
  dgemm_kernel<2><<<gmix, 256, 0, stream>>>(htb, Lt, omzb, Rt, bias, Ws,
      Pc0, nullptr, scA, nullptr, nullptr, nullptr, nullptr);
  lmix_kernel<<<4096, 256, 0, stream>>>(Pc0, scA, out_gnode + 6 * 256, ztb,
      nullptr, part + 3 * 4096 * 4);

  // h_next = mix(zt@L + z2h@R + b)
  dgemm_kernel<0><<<gmix, 256, 0, stream>>>(ztb, Lt, z2hb, Rt, bias, Ws,
      Pc0, nullptr, scA, nullptr, nullptr, nullptr, nullptr);
  lmix_kernel<<<4096, 256, 0, stream>>>(Pc0, scA, out_gnode + 8 * 256, nullptr,
      out_hnext, part + 5 * 4096 * 4);

  fin_kernel<<<1, 256, 0, stream>>>(part, out_gs, out_marg);
}

// Round 3
// 695.135 us; speedup vs baseline: 1.0144x; 1.0144x over previous
//
#include <hip/hip_runtime.h>

typedef __bf16 bf16_t;
typedef bf16_t bf16x8 __attribute__((ext_vector_type(8)));
typedef float f32x4 __attribute__((ext_vector_type(4)));

#define BATCH 16384
#define HID 256

// ---------- bf16 helpers ----------
__device__ __forceinline__ ushort f2b(float f) {
  union { float f; unsigned u; } v; v.f = f;
  unsigned u = v.u;
  unsigned r = (u + 0x7fffu + ((u >> 16) & 1u)) >> 16;
  return (ushort)r;
}
__device__ __forceinline__ float b2f(ushort u) {
  union { unsigned u; float f; } v; v.u = ((unsigned)u) << 16; return v.f;
}
__device__ __forceinline__ void loadbf4(const ushort* __restrict__ p, float* o) {
  uint2 q = *(const uint2*)p;
  o[0] = b2f((ushort)(q.x & 0xffffu));
  o[1] = b2f((ushort)(q.x >> 16));
  o[2] = b2f((ushort)(q.y & 0xffffu));
  o[3] = b2f((ushort)(q.y >> 16));
}
__device__ __forceinline__ uint2 packbf4(const float* v) {
  uint2 q;
  q.x = (unsigned)f2b(v[0]) | ((unsigned)f2b(v[1]) << 16);
  q.y = (unsigned)f2b(v[2]) | ((unsigned)f2b(v[3]) << 16);
  return q;
}

// async global->LDS, 16B/lane; LDS base wave-uniform
__device__ __forceinline__ void gll16(const ushort* g, ushort* l) {
  __builtin_amdgcn_global_load_lds((const __attribute__((address_space(1))) void*)g,
                                   (__attribute__((address_space(3))) void*)l, 16, 0, 0);
}

// ---------- fp32 -> bf16 ----------
__global__ __launch_bounds__(256)
void f2b_kernel(const float* __restrict__ in, ushort* __restrict__ out) {
  int t = blockIdx.x * 256 + threadIdx.x;
  float4 v = *(const float4*)(in + (size_t)t * 4);
  float a[4] = {v.x, v.y, v.z, v.w};
  *(uint2*)(out + (size_t)t * 4) = packbf4(a);
}

// ---------- transposed bf16 weights: Wt[ksel*256+d][h] = W[ksel][h][d] ----------
__global__ __launch_bounds__(256)
void wt_kernel(const float* __restrict__ W, ushort* __restrict__ Wt) {
  int idx = blockIdx.x * 256 + threadIdx.x;
  int c = idx >> 8, hh = idx & 255;
  int ks = c >> 8, d = c & 255;
  Wt[idx] = f2b(W[ks * 65536 + hh * 256 + d]);
}

// ---------- single-accumulator GEMM + fused epilogue ----------
// MODE 0: K=512 ([A1|A2]@[W1;W2]), cand = C+b          -> Pc + score
// MODE 1: K=512, N=512, sigmoid(C+b)                   -> gnode 0/1/2 + z1b/rb
// MODE 2: K=256, raw C -> Pz  AND cand = 1-(C+b)       -> Pc + score
// MODE 3: K=256, cand = C * Pz + b                     -> Pc + score
// MODE 4: K=256, raw C -> Pz only
template<int MODE>
__global__ __launch_bounds__(256, 2)
void ggemm_kernel(const ushort* __restrict__ A1, const ushort* __restrict__ W1,
                  const ushort* __restrict__ A2, const ushort* __restrict__ W2,
                  const float* __restrict__ bias, const float* __restrict__ Ws,
                  ushort* __restrict__ Pc, ushort* __restrict__ Pz,
                  float* __restrict__ score, float* __restrict__ gnode,
                  ushort* __restrict__ z1b, ushort* __restrict__ rb) {
  constexpr int KT = (MODE <= 1) ? 16 : 8;
  __shared__ ushort As[4096], Bs[4096];    // [128 rows][32 k], XOR-swizzled chunks
  __shared__ float sbuf[128][2];
  const int tid  = threadIdx.x;
  const int lane = tid & 63;
  const int w    = tid >> 6;
  const int bm   = blockIdx.y * 128;
  const int bnc  = blockIdx.x * 128;

  // staging: lane -> row rl=lane>>2 (within 16-row group), chunk cc=lane&3;
  // global chunk fetched = cc ^ s(row); LDS holds chunk pos cc (swizzled content)
  const int rl = lane >> 2, cc = lane & 3;
  const int cs = (cc ^ (rl & 3) ^ ((rl >> 2) & 3)) * 8;
  const int sr0 = w * 16 + rl, sr1 = sr0 + 64;
  const ushort* a1g0 = A1 + (size_t)(bm + sr0) * 256 + cs;
  const ushort* a1g1 = A1 + (size_t)(bm + sr1) * 256 + cs;
  const ushort* w1g0 = W1 + (size_t)(bnc + sr0) * 256 + cs;
  const ushort* w1g1 = W1 + (size_t)(bnc + sr1) * 256 + cs;
  const ushort* a2g0 = a1g0, *a2g1 = a1g1, *w2g0 = w1g0, *w2g1 = w1g1;
  if constexpr (MODE <= 1) {
    a2g0 = A2 + (size_t)(bm + sr0) * 256 + cs;
    a2g1 = A2 + (size_t)(bm + sr1) * 256 + cs;
    w2g0 = W2 + (size_t)(bnc + sr0) * 256 + cs;
    w2g1 = W2 + (size_t)(bnc + sr1) * 256 + cs;
  }
  ushort* lA0 = &As[w * 512]; ushort* lA1v = &As[(w + 4) * 512];
  ushort* lB0 = &Bs[w * 512]; ushort* lB1v = &Bs[(w + 4) * 512];

  const int row15 = lane & 15, quad = lane >> 4;
  const int fs = (quad ^ (row15 & 3) ^ ((row15 >> 2) & 3)) * 8;  // swizzled read pos
  const int wm = (w >> 1) * 64, wn = (w & 1) * 64;

  f32x4 acc[4][4] = {};

  for (int kt = 0; kt < KT; ++kt) {
    const int k0 = (kt & 7) * 32;
    const ushort *ag0 = a1g0, *ag1 = a1g1, *wg0 = w1g0, *wg1 = w1g1;
    if constexpr (MODE <= 1)
      if (kt >= 8) { ag0 = a2g0; ag1 = a2g1; wg0 = w2g0; wg1 = w2g1; }
    __syncthreads();                   // readers of previous kt done
    gll16(ag0 + k0, lA0); gll16(ag1 + k0, lA1v);
    gll16(wg0 + k0, lB0); gll16(wg1 + k0, lB1v);
    __syncthreads();                   // vmcnt drained before barrier release
    bf16x8 bfr[4];
    for (int tj = 0; tj < 4; ++tj)
      bfr[tj] = *(const bf16x8*)&Bs[(wn + tj * 16 + row15) * 32 + fs];
    for (int ti = 0; ti < 4; ++ti) {
      bf16x8 afr = *(const bf16x8*)&As[(wm + ti * 16 + row15) * 32 + fs];
      for (int tj = 0; tj < 4; ++tj)
        acc[ti][tj] = __builtin_amdgcn_mfma_f32_16x16x32_bf16(afr, bfr[tj], acc[ti][tj], 0, 0, 0);
    }
  }

  if constexpr (MODE == 1) {
    const bool isz = (bnc < 256);            // cols [0,256): z1 ; [256,512): r
    for (int ti = 0; ti < 4; ++ti)
      for (int tj = 0; tj < 4; ++tj) {
        int gnc = bnc + wn + tj * 16 + row15;
        float bb = bias[gnc];
        for (int r2 = 0; r2 < 4; ++r2) {
          int gm = bm + wm + ti * 16 + quad * 4 + r2;
          float v = 1.0f / (1.0f + expf(-(acc[ti][tj][r2] + bb)));
          if (isz) {
            gnode[(size_t)gm * 2304 + gnc] = v;
            gnode[(size_t)gm * 2304 + 512 + gnc] = v;
            z1b[(size_t)gm * 256 + gnc] = f2b(v);
          } else {
            int d = gnc - 256;
            gnode[(size_t)gm * 2304 + 256 + d] = v;
            rb[(size_t)gm * 256 + d] = f2b(v);
          }
        }
      }
  } else if constexpr (MODE == 4) {
    for (int ti = 0; ti < 4; ++ti) {
      int gm0 = bm + wm + ti * 16 + quad * 4;
      for (int tj = 0; tj < 4; ++tj) {
        int gnc = bnc + wn + tj * 16 + row15;
        for (int r2 = 0; r2 < 4; ++r2)
          Pz[(size_t)(gm0 + r2) * 1024 + gnc] = f2b(acc[ti][tj][r2]);
      }
    }
  } else {
    float wsv[4], bv[4]; int gnc4[4];
    for (int tj = 0; tj < 4; ++tj) {
      int gnc = bnc + wn + tj * 16 + row15;
      gnc4[tj] = gnc; wsv[tj] = Ws[gnc & 255]; bv[tj] = bias[gnc];
    }
    float pA[4][4];
    for (int ti = 0; ti < 4; ++ti) {
      int gm0 = bm + wm + ti * 16 + quad * 4;
      for (int r2 = 0; r2 < 4; ++r2) pA[ti][r2] = 0.f;
      for (int tj = 0; tj < 4; ++tj)
        for (int r2 = 0; r2 < 4; ++r2) {
          float c = acc[ti][tj][r2];
          float ca;
          if constexpr (MODE == 0) ca = c + bv[tj];
          else if constexpr (MODE == 2) {
            Pz[(size_t)(gm0 + r2) * 1024 + gnc4[tj]] = f2b(c);
            ca = 1.0f - (c + bv[tj]);
          } else {  // MODE 3
            float pz = b2f(Pz[(size_t)(gm0 + r2) * 1024 + gnc4[tj]]);
            ca = c * pz + bv[tj];
          }
          Pc[(size_t)(gm0 + r2) * 1024 + gnc4[tj]] = f2b(ca);
          pA[ti][r2] += ca * wsv[tj];
        }
    }
    for (int ti = 0; ti < 4; ++ti)
      for (int r2 = 0; r2 < 4; ++r2) {
        float v = pA[ti][r2];
        v += __shfl_xor(v, 1, 64); v += __shfl_xor(v, 2, 64);
        v += __shfl_xor(v, 4, 64); v += __shfl_xor(v, 8, 64);
        if (row15 == 0) sbuf[wm + ti * 16 + quad * 4 + r2][wn >> 6] = v;
      }
    __syncthreads();
    if (tid < 128)
      score[(size_t)(bm + tid) * 8 + blockIdx.x] = sbuf[tid][0] + sbuf[tid][1];
  }
}

// ---------- light mixture: softmax from 8 score halves, weighted cand sum ----------
__global__ __launch_bounds__(256)
void lmix_kernel(const ushort* __restrict__ Pc, const float* __restrict__ sb,
                 float* __restrict__ gnode, ushort* __restrict__ actout,
                 float* __restrict__ hnext, float* __restrict__ part) {
  const int tid = threadIdx.x, wave = tid >> 6, lane = tid & 63;
  const int row = blockIdx.x * 4 + wave;
  const int d0 = lane * 4;
  const float* sp = sb + (size_t)row * 8;
  float s0 = sp[0] + sp[1], s1 = sp[2] + sp[3], s2 = sp[4] + sp[5], s3 = sp[6] + sp[7];
  float mx = fmaxf(fmaxf(s0, s1), fmaxf(s2, s3));
  float e0 = expf(s0 - mx), e1 = expf(s1 - mx), e2 = expf(s2 - mx), e3 = expf(s3 - mx);
  float inv = 1.0f / (e0 + e1 + e2 + e3);
  float w0 = e0 * inv, w1 = e1 * inv, w2 = e2 * inv, w3 = e3 * inv;
  float c0[4], c1[4], c2[4], c3[4];
  loadbf4(Pc + (size_t)row * 1024 + 0 + d0, c0);
  loadbf4(Pc + (size_t)row * 1024 + 256 + d0, c1);
  loadbf4(Pc + (size_t)row * 1024 + 512 + d0, c2);
  loadbf4(Pc + (size_t)row * 1024 + 768 + d0, c3);
  float o[4];
  for (int i = 0; i < 4; ++i) o[i] = w0 * c0[i] + w1 * c1[i] + w2 * c2[i] + w3 * c3[i];
  size_t g = (size_t)row * 2304 + d0;
  for (int i = 0; i < 4; ++i) gnode[g + i] = o[i];
  if (actout) *(uint2*)(actout + (size_t)row * 256 + d0) = packbf4(o);
  if (hnext) { float4 ov = {o[0], o[1], o[2], o[3]}; *(float4*)(hnext + (size_t)row * 256 + d0) = ov; }
  __shared__ float sred[4][4];
  if (lane == 0) { sred[wave][0] = s0; sred[wave][1] = s1; sred[wave][2] = s2; sred[wave][3] = s3; }
  __syncthreads();
  if (tid < 4)
    part[blockIdx.x * 4 + tid] = sred[0][tid] + sred[1][tid] + sred[2][tid] + sred[3][tid];
}

// ---------- finalize ----------
__global__ __launch_bounds__(256)
void fin_kernel(const float* __restrict__ part, float* __restrict__ gs,
                float* __restrict__ margins) {
  __shared__ float red[256][4];
  __shared__ float sfin[6][4];
  int tid = threadIdx.x;
  for (int si = 0; si < 6; ++si) {
    float a[4] = {0.f, 0.f, 0.f, 0.f};
    for (int i = 0; i < 16; ++i) {
      const float* p = part + ((size_t)si * 4096 + tid + 256 * i) * 4;
      for (int k = 0; k < 4; ++k) a[k] += p[k];
    }
    for (int k = 0; k < 4; ++k) red[tid][k] = a[k];
    __syncthreads();
    for (int st = 128; st >= 1; st >>= 1) {
      if (tid < st) for (int k = 0; k < 4; ++k) red[tid][k] += red[tid + st][k];
      __syncthreads();
    }
    if (tid == 0) for (int k = 0; k < 4; ++k) sfin[si][k] = red[0][k];
    __syncthreads();
  }
  if (tid == 0) {
    gs[0] = 0.f; gs[1] = 1.f; gs[2] = 0.f;
    for (int si = 0; si < 6; ++si) {
      float s[4] = {sfin[si][0], sfin[si][1], sfin[si][2], sfin[si][3]};
      int idx = 0; float best = s[0];
      for (int k = 1; k < 4; ++k) if (s[k] > best) { best = s[k]; idx = k; }
      float second = -3.4e38f;
      for (int k = 0; k < 4; ++k) if (k != idx) second = fmaxf(second, s[k]);
      gs[3 + si] = (float)idx;
      margins[si] = best - second;
    }
  }
}

extern "C" void kernel_launch(void* const* d_in, const int* in_sizes, int n_in,
                              void* d_out, int out_size, void* d_ws, size_t ws_size,
                              hipStream_t stream) {
  const float* x    = (const float*)d_in[0];
  const float* h    = (const float*)d_in[1];
  const float* L    = (const float*)d_in[2];
  const float* R    = (const float*)d_in[3];
  const float* bias = (const float*)d_in[4];
  const float* Ws   = (const float*)d_in[5];

  float* out        = (float*)d_out;
  float* out_hnext  = out;                          // 4,194,304
  float* out_gs     = out + 4194304;                // 9
  float* out_gnode  = out + 4194313;                // 16384*9*256
  float* out_marg   = out + 41943049;               // 6

  ushort* Pc   = (ushort*)d_ws;                     // B*1024
  ushort* Pz   = Pc + (size_t)BATCH * 1024;         // B*1024
  ushort* x2b  = Pz + (size_t)BATCH * 1024;
  ushort* h2b  = x2b + (size_t)BATCH * HID;
  ushort* z1b  = h2b + (size_t)BATCH * HID;
  ushort* rb   = z1b + (size_t)BATCH * HID;
  ushort* rhb  = rb  + (size_t)BATCH * HID;
  ushort* htb  = rhb + (size_t)BATCH * HID;
  ushort* omzb = htb + (size_t)BATCH * HID;
  ushort* ztb  = omzb + (size_t)BATCH * HID;
  ushort* z2hb = ztb + (size_t)BATCH * HID;
  ushort* Lt   = z2hb + (size_t)BATCH * HID;        // 1024*256
  ushort* Rt   = Lt + 1024 * 256;
  float*  scA  = (float*)(Rt + 1024 * 256);         // [16384][8]
  float*  part = scA + (size_t)BATCH * 8;           // 6*4096*4

  dim3 gmix(8, 128), gsig(4, 128);

  f2b_kernel<<<4096, 256, 0, stream>>>(x, x2b);
  f2b_kernel<<<4096, 256, 0, stream>>>(h, h2b);
  wt_kernel<<<1024, 256, 0, stream>>>(L, Lt);
  wt_kernel<<<1024, 256, 0, stream>>>(R, Rt);

  // sig: z1 = sig([x|h]@[L0;R0]), r = sig([x|h]@[L1;R1])   (K=512, N=512)
  ggemm_kernel<1><<<gsig, 256, 0, stream>>>(x2b, Lt, h2b, Rt, bias, nullptr,
      nullptr, nullptr, nullptr, out_gnode, z1b, rb);

  // rh = mix([h|r]@[L;R] + b)
  ggemm_kernel<0><<<gmix, 256, 0, stream>>>(h2b, Lt, rb, Rt, bias, Ws,
      Pc, nullptr, scA, nullptr, nullptr, nullptr);
  lmix_kernel<<<4096, 256, 0, stream>>>(Pc, scA, out_gnode + 3 * 256, rhb,
      nullptr, part + 0 * 4096 * 4);

  // h_tilde = mix([x|rh]@[L;R] + b)
  ggemm_kernel<0><<<gmix, 256, 0, stream>>>(x2b, Lt, rhb, Rt, bias, Ws,
      Pc, nullptr, scA, nullptr, nullptr, nullptr);
  lmix_kernel<<<4096, 256, 0, stream>>>(Pc, scA, out_gnode + 4 * 256, htb,
      nullptr, part + 1 * 4096 * 4);

  // z1@R raw -> Pz ; omz cand = 1-(z1@R+b) -> Pc
  ggemm_kernel<2><<<gmix, 256, 0, stream>>>(z1b, Rt, nullptr, nullptr, bias, Ws,
      Pc, Pz, scA, nullptr, nullptr, nullptr);
  lmix_kernel<<<4096, 256, 0, stream>>>(Pc, scA, out_gnode + 5 * 256, omzb,
      nullptr, part + 2 * 4096 * 4);

  // z2h cand = (h@L) * Pz + b
  ggemm_kernel<3><<<gmix, 256, 0, stream>>>(h2b, Lt, nullptr, nullptr, bias, Ws,
      Pc, Pz, scA, nullptr, nullptr, nullptr);
  lmix_kernel<<<4096, 256, 0, stream>>>(Pc, scA, out_gnode + 7 * 256, z2hb,
      nullptr, part + 4 * 4096 * 4);

  // omz@R raw -> Pz
  ggemm_kernel<4><<<gmix, 256, 0, stream>>>(omzb, Rt, nullptr, nullptr, bias, nullptr,
      nullptr, Pz, nullptr, nullptr, nullptr, nullptr);

  // zh_tilde cand = (ht@L) * Pz + b
  ggemm_kernel<3><<<gmix, 256, 0, stream>>>(htb, Lt, nullptr, nullptr, bias, Ws,
      Pc, Pz, scA, nullptr, nullptr, nullptr);
  lmix_kernel<<<4096, 256, 0, stream>>>(Pc, scA, out_gnode + 6 * 256, ztb,
      nullptr, part + 3 * 4096 * 4);

  // h_next = mix([zt|z2h]@[L;R] + b)
  ggemm_kernel<0><<<gmix, 256, 0, stream>>>(ztb, Lt, z2hb, Rt, bias, Ws,
      Pc, nullptr, scA, nullptr, nullptr, nullptr);
  lmix_kernel<<<4096, 256, 0, stream>>>(Pc, scA, out_gnode + 8 * 256, nullptr,
      out_hnext, part + 5 * 4096 * 4);

  fin_kernel<<<1, 256, 0, stream>>>(part, out_gs, out_marg);
}